// Round 6
// baseline (336.260 us; speedup 1.0000x reference)
//
#include <hip/hip_runtime.h>

// PETP_Quadratic R9: 4-blocks/CU geometry.
//   R8 post-mortem: 384-thr blocks never co-schedule (1 block/CU at 61.4K and
//   70.7K LDS); 192-thr blocks do (R4: ~4 blocks at 26K, R5/R6: 2 at ~51-63K).
//   MfmaUtil 22.4% == exactly 1.5 waves/SIMD of scheduled MFMA work -> wall
//   is residency-bound, not pipe-bound.
//   R9: 192-thr (3-wave) block owns 16 batches = 96 pos; feat 24,576 B;
//   staging chunk = one (u,kh) half-step = 3 frags {A,G,V} = 3 KB, x2 bufs.
//   Total LDS 30,720 -> 4 blocks/CU = 12 waves/CU = 3 waves/SIMD. Grid 1024
//   = exactly 4/CU, one generation. 1 DMA per wave per chunk (3 frags/3
//   waves). Protocol: {s_barrier; sched_barrier; issue DMA(c+1); vmcnt(1)
//   [c landed, c+1 in flight]; 5 MFMAs}. Never drain vmcnt in-loop.
//   Feat build: float4 loads (512 items vs 2048 scalar).

typedef _Float16 half8   __attribute__((ext_vector_type(8)));
typedef _Float16 half4_t __attribute__((ext_vector_type(4)));
typedef float    f32x16  __attribute__((ext_vector_type(16)));
typedef float    float4_t __attribute__((ext_vector_type(4)));

#define NORM 0.022097086912079608f   /* 1/(32*sqrt(2)) */
#define INV_SQRT3 0.5773502691896258f

// ---------------- prep: fragment-swizzled f16 weights ----------------
// Global frag index = ((t*32+u)*2+kh)*3 + fr, fr in {0=A,1=G,2=V}; frag is
// 512 half (1KB): element lane*8+j with lane n = lane&31, kq = lane>>5,
// k-channel v = kh*16 + kq*8 + j.
//   A: NORM*W0[u][v][n]   G: NORM*INV_SQRT3*W1[u][v][n]
//   V: NORM*(W2[u][v][n] + W3[v][u][n])
__global__ void prep_kernel(const float* __restrict__ Wa, const float* __restrict__ Wb,
                            const float* __restrict__ Wc, const float* __restrict__ Wd,
                            _Float16* __restrict__ Ball) {
    int idx = blockIdx.x * 256 + threadIdx.x;   // 0..49151
    if (idx >= 49152) return;
    int lane = idx & 63;
    int frag = idx >> 6;          // 0..767, wave-uniform
    int fr = frag % 3;
    int q  = frag / 3;            // (t*32+u)*2+kh
    int kh = q & 1;
    int u  = (q >> 1) & 31;
    int t  = q >> 6;
    int n = lane & 31, kq = lane >> 5;
    const float* Ws[4] = {Wa, Wb, Wc, Wd};
    const float* W = Ws[t];
    half8 out;
#pragma unroll
    for (int j = 0; j < 8; ++j) {
        int v = kh * 16 + kq * 8 + j;
        float val;
        if (fr == 0)      val = NORM * W[u * 1024 + v * 32 + n];
        else if (fr == 1) val = NORM * INV_SQRT3 * W[32768 + u * 1024 + v * 32 + n];
        else              val = NORM * (W[65536 + u * 1024 + v * 32 + n] +
                                        W[98304 + v * 1024 + u * 32 + n]);
        out[j] = (_Float16)val;
    }
    *(half8*)(Ball + (size_t)frag * 512 + lane * 8) = out;
}

// async global->LDS, 16B per lane. LDS dest = wave-uniform base + lane*16.
__device__ __forceinline__ void gload_lds16(const _Float16* g, _Float16* l) {
    __builtin_amdgcn_global_load_lds(
        (const __attribute__((address_space(1))) unsigned int*)g,
        (__attribute__((address_space(3))) unsigned int*)l, 16, 0, 0);
}

// ---------------- main kernel ----------------
// WG = 192 thr (3 waves) owns 16 batches = 96 positions; wave owns 32 (one
// M-tile). feat[pos][ch] pos-major, 16B-chunk XOR swizzle:
// half index = pos*128 + (((ch>>3) ^ (pos&7))<<3) + (ch&7).
__launch_bounds__(192, 3)
__global__ void petp_main(const float* __restrict__ x,
                          const _Float16* __restrict__ Ball,
                          float* __restrict__ y) {
    __shared__ _Float16 feat[96 * 128];   // 24,576 B
    __shared__ _Float16 Bst[2][1536];     // 2 x 3 KB (chunk = one (u,kh))

    const int tid  = threadIdx.x;
    const int wave = tid >> 6;
    const int lane = tid & 63;
    const int mw = lane & 31;   // A row (position in tile) AND C/D col n
    const int q8 = lane >> 5;   // k-quad within a K=16 MFMA
    const int wvu = __builtin_amdgcn_readfirstlane(wave);   // 0..2 = frag slot

    f32x16 acc_s;
    f32x16 acc_v[3];
#pragma unroll
    for (int r = 0; r < 16; ++r) {
        acc_s[r] = 0.f; acc_v[0][r] = 0.f; acc_v[1][r] = 0.f; acc_v[2][r] = 0.f;
    }

    const int wg = blockIdx.x;
    const float* xg = x + (size_t)wg * (96 * 128);

    const _Float16* fpos = feat + (wave * 32 + mw) * 128;
    const int px = mw & 7;   // pos&7 for my lane (wave*32 is 8-aligned)

    half8 sl_s[2];       // per-lane A-side k-slices, persistent per variant
    half8 sl_v[2][3];

#pragma unroll 1
    for (int t = 0; t < 4; ++t) {
        const _Float16* Bt = Ball + t * 98304;

        // prologue: DMA chunk 0 (lands during feat build). Safe vs prior
        // variant: all waves passed barrier-63, so buf0 readers are done.
        gload_lds16(Bt + wvu * 512 + lane * 8, &Bst[0][wvu * 512]);

        // ---- build variant-t features (float4 loads) ----
#pragma unroll
        for (int it = 0; it < 3; ++it) {
            int item = it * 192 + tid;        // 16 batches x 32 ch-groups
            if (item < 512) {
                int b  = item >> 5;
                int cg = item & 31;
                const float* bp = xg + b * 768 + cg * 4;
                float4_t v00 = *(const float4_t*)(bp);
                float4_t v01 = *(const float4_t*)(bp + 128);
                float4_t v02 = *(const float4_t*)(bp + 256);
                float4_t v10 = *(const float4_t*)(bp + 384);
                float4_t v11 = *(const float4_t*)(bp + 512);
                float4_t v12 = *(const float4_t*)(bp + 640);
                float4_t rs0 = v00 + v01 + v02, rs1 = v10 + v11 + v12;
                float4_t tot = rs0 + rs1;
                float4_t xv[6] = {v00, v01, v02, v10, v11, v12};
                float4_t rs[2] = {rs0, rs1};
                float4_t cs[3] = {v00 + v10, v01 + v11, v02 + v12};
#pragma unroll
                for (int p6 = 0; p6 < 6; ++p6) {
                    int i = p6 / 3, j = p6 % 3;
                    float4_t f;
                    if      (t == 0) f = xv[p6];
                    else if (t == 1) f = (rs[i] - xv[p6]) * 0.5f;
                    else if (t == 2) f = cs[j] - xv[p6];
                    else             f = (tot - rs[i] - cs[j] + xv[p6]) * 0.5f;
                    int pos = b * 6 + p6;
                    int base = pos * 128;
                    int pxs = pos & 7;
                    if (cg < 8) {   // s-rows: 4 contiguous halves, one b64 store
                        int row0 = cg * 4;
                        int addr = base + ((((row0 >> 3) ^ pxs) << 3) | (row0 & 7));
                        half4_t h4 = {(_Float16)f[0], (_Float16)f[1],
                                      (_Float16)f[2], (_Float16)f[3]};
                        *(half4_t*)(feat + addr) = h4;
                    } else {        // v-rows: scattered
#pragma unroll
                        for (int c4 = 0; c4 < 4; ++c4) {
                            int cc = cg * 4 + c4 - 32;
                            int row = 32 + (cc % 3) * 32 + cc / 3;
                            feat[base + ((((row >> 3) ^ pxs) << 3) | (row & 7))] =
                                (_Float16)f[c4];
                        }
                    }
                }
            }
        }
        asm volatile("s_waitcnt lgkmcnt(0)" ::: "memory");   // my feat writes done

        half8 bcS, bcG0, bcG1, bcG2;   // broadcast chunk: 8 u-values, registers

        // ---- 64 chunks (u,kh); depth-1 DMA, counted vmcnt(1) ----
#pragma unroll 1
        for (int cb = 0; cb < 4; ++cb) {
#pragma unroll
            for (int k = 0; k < 16; ++k) {
                // barrier: all waves done reading buf (k+1)&1 (iter c-1);
                // at c==0 also publishes feat (each wave drained lgkm above).
                __builtin_amdgcn_s_barrier();
                __builtin_amdgcn_sched_barrier(0);   // pin DMA issue after barrier

                if (k < 15) {
                    gload_lds16(Bt + ((cb * 16 + k + 1) * 3 + wvu) * 512 + lane * 8,
                                &Bst[(k + 1) & 1][wvu * 512]);
                    asm volatile("s_waitcnt vmcnt(1)" ::: "memory");  // c landed
                } else if (cb < 3) {
                    gload_lds16(Bt + (((cb + 1) * 16) * 3 + wvu) * 512 + lane * 8,
                                &Bst[0][wvu * 512]);
                    asm volatile("s_waitcnt vmcnt(1)" ::: "memory");
                } else {
                    asm volatile("s_waitcnt vmcnt(0)" ::: "memory");  // tail drain
                }
                __builtin_amdgcn_sched_barrier(0);

                if (cb == 0 && k == 0) {   // per-lane A-side slices, once/variant
#pragma unroll
                    for (int kh = 0; kh < 2; ++kh) {
                        sl_s[kh] = *(const half8*)(fpos + (((kh * 2 + q8) ^ px) << 3));
#pragma unroll
                        for (int i = 0; i < 3; ++i)
                            sl_v[kh][i] = *(const half8*)(fpos + (((4 + i * 4 + kh * 2 + q8) ^ px) << 3));
                    }
                }
                if (k == 0) {   // broadcast chunk for u = cb*8 .. cb*8+7
                    bcS  = *(const half8*)(fpos + ((cb ^ px) << 3));
                    bcG0 = *(const half8*)(fpos + (((4 + cb) ^ px) << 3));
                    bcG1 = *(const half8*)(fpos + (((8 + cb) ^ px) << 3));
                    bcG2 = *(const half8*)(fpos + (((12 + cb) ^ px) << 3));
                }

                const int kh = k & 1;        // compile-time
                const int uu = k >> 1;       // compile-time, 0..7
                const _Float16* F = &Bst[kh][lane * 8];
                __builtin_amdgcn_s_setprio(1);
                {
                    half8 bA = *(const half8*)(F);
                    half8 bG = *(const half8*)(F + 512);
                    half8 bV = *(const half8*)(F + 1024);
                    _Float16 su = bcS[uu];
                    _Float16 g0 = bcG0[uu], g1 = bcG1[uu], g2 = bcG2[uu];

                    half8 af;
                    // ---- ys: s.s^T ----
                    af = sl_s[kh] * su;
                    acc_s = __builtin_amdgcn_mfma_f32_32x32x16_f16(af, bA, acc_s, 0, 0, 0);
                    // ---- ys: Gram(v) ----
                    af = sl_v[kh][0] * g0 + sl_v[kh][1] * g1 + sl_v[kh][2] * g2;
                    acc_s = __builtin_amdgcn_mfma_f32_32x32x16_f16(af, bG, acc_s, 0, 0, 0);
                    // ---- yv: s[u] v[v,kc], V-frag shared across kc ----
#pragma unroll
                    for (int kc = 0; kc < 3; ++kc) {
                        half8 afv = sl_v[kh][kc] * su;
                        acc_v[kc] = __builtin_amdgcn_mfma_f32_32x32x16_f16(afv, bV, acc_v[kc], 0, 0, 0);
                    }
                }
                __builtin_amdgcn_s_setprio(0);
            }
        }
    }

    // ---- epilogue: 32x32 C/D layout col(n)=lane&31, row=(reg&3)+8*(reg>>2)+4*q8 ----
    float* yg = y + (size_t)wg * (96 * 128);
    const int pb = wave * 32 + q8 * 4;
#pragma unroll
    for (int r = 0; r < 16; ++r) {
        int pos = pb + (r & 3) + 8 * (r >> 2);
        float* yp = yg + pos * 128;
        __builtin_nontemporal_store(acc_s[r], yp + mw);
        __builtin_nontemporal_store(acc_v[0][r], yp + 32 + 3 * mw + 0);
        __builtin_nontemporal_store(acc_v[1][r], yp + 32 + 3 * mw + 1);
        __builtin_nontemporal_store(acc_v[2][r], yp + 32 + 3 * mw + 2);
    }
}

extern "C" void kernel_launch(void* const* d_in, const int* in_sizes, int n_in,
                              void* d_out, int out_size, void* d_ws, size_t ws_size,
                              hipStream_t stream) {
    const float* x  = (const float*)d_in[0];
    const float* Wa = (const float*)d_in[1];
    const float* Wb = (const float*)d_in[2];
    const float* Wc = (const float*)d_in[3];
    const float* Wd = (const float*)d_in[4];
    float* y = (float*)d_out;

    _Float16* Ball = (_Float16*)d_ws;          // 393216 half = 768 KB

    int nbatch = in_sizes[0] / 768;            // 16384
    int nwg = nbatch / 16;                     // 1024 = 4 blocks/CU exactly

    prep_kernel<<<192, 256, 0, stream>>>(Wa, Wb, Wc, Wd, Ball);
    petp_main<<<nwg, 192, 0, stream>>>(x, Ball, y);
}

// Round 7
// 318.533 us; speedup vs baseline: 1.0557x; 1.0557x over previous
//
#include <hip/hip_runtime.h>

// PETP_Quadratic R10: barrier-free register-streamed B.
//   R9 post-mortem: occupancy fix worked (34%) but per-chunk wall (~2400 cyc)
//   is the barrier+depth-1-DMA protocol itself; MfmaUtil pinned at 22% at any
//   occupancy. Also: 4 DMA streams/CU thrashed L2 (FETCH 220MB) and NT
//   partial-line stores amplified writes (117MB).
//   R10: NO in-loop barriers, NO LDS staging for B. Each wave streams its own
//   B fragments global->registers (3x global_load_dwordx4 per chunk, depth-2
//   rotation, compiler-counted vmcnt). B is L2/L1-resident (768 KB total, 12
//   waves/CU re-read the same chunks within a short window). LDS = feat only
//   (24,576 B). Plain stores (L2 merges partial lines). 2 barriers/variant
//   (around feat build) only.

typedef _Float16 half8   __attribute__((ext_vector_type(8)));
typedef _Float16 half4_t __attribute__((ext_vector_type(4)));
typedef float    f32x16  __attribute__((ext_vector_type(16)));
typedef float    float4_t __attribute__((ext_vector_type(4)));

#define NORM 0.022097086912079608f   /* 1/(32*sqrt(2)) */
#define INV_SQRT3 0.5773502691896258f

// ---------------- prep: fragment-swizzled f16 weights ----------------
// Chunk c = u*2+kh (64 per variant); frag index = (t*64+c)*3 + fr,
// fr in {0=A,1=G,2=V}; frag = 512 half (1KB): element lane*8+j with
// lane n = lane&31, kq = lane>>5, k-channel v = kh*16 + kq*8 + j.
//   A: NORM*W0[u][v][n]   G: NORM*INV_SQRT3*W1[u][v][n]
//   V: NORM*(W2[u][v][n] + W3[v][u][n])
__global__ void prep_kernel(const float* __restrict__ Wa, const float* __restrict__ Wb,
                            const float* __restrict__ Wc, const float* __restrict__ Wd,
                            _Float16* __restrict__ Ball) {
    int idx = blockIdx.x * 256 + threadIdx.x;   // 0..49151
    if (idx >= 49152) return;
    int lane = idx & 63;
    int frag = idx >> 6;          // 0..767, wave-uniform
    int fr = frag % 3;
    int q  = frag / 3;            // t*64 + u*2 + kh
    int kh = q & 1;
    int u  = (q >> 1) & 31;
    int t  = q >> 6;
    int n = lane & 31, kq = lane >> 5;
    const float* Ws[4] = {Wa, Wb, Wc, Wd};
    const float* W = Ws[t];
    half8 out;
#pragma unroll
    for (int j = 0; j < 8; ++j) {
        int v = kh * 16 + kq * 8 + j;
        float val;
        if (fr == 0)      val = NORM * W[u * 1024 + v * 32 + n];
        else if (fr == 1) val = NORM * INV_SQRT3 * W[32768 + u * 1024 + v * 32 + n];
        else              val = NORM * (W[65536 + u * 1024 + v * 32 + n] +
                                        W[98304 + v * 1024 + u * 32 + n]);
        out[j] = (_Float16)val;
    }
    *(half8*)(Ball + (size_t)frag * 512 + lane * 8) = out;
}

// ---------------- main kernel ----------------
// WG = 192 thr (3 waves) owns 16 batches = 96 positions; wave owns 32 (one
// M-tile). feat[pos][ch] pos-major, 16B-chunk XOR swizzle:
// half index = pos*128 + (((ch>>3) ^ (pos&7))<<3) + (ch&7).
__launch_bounds__(192, 3)
__global__ void petp_main(const float* __restrict__ x,
                          const _Float16* __restrict__ Ball,
                          float* __restrict__ y) {
    __shared__ _Float16 feat[96 * 128];   // 24,576 B (feat only; no B staging)

    const int tid  = threadIdx.x;
    const int wave = tid >> 6;
    const int lane = tid & 63;
    const int mw = lane & 31;   // A row (position in tile) AND C/D col n
    const int q8 = lane >> 5;   // k-quad within a K=16 MFMA

    f32x16 acc_s;
    f32x16 acc_v[3];
#pragma unroll
    for (int r = 0; r < 16; ++r) {
        acc_s[r] = 0.f; acc_v[0][r] = 0.f; acc_v[1][r] = 0.f; acc_v[2][r] = 0.f;
    }

    const int wg = blockIdx.x;
    const float* xg = x + (size_t)wg * (96 * 128);

    const _Float16* fpos = feat + (wave * 32 + mw) * 128;
    const int px = mw & 7;   // pos&7 for my lane (wave*32 is 8-aligned)

    half8 sl_s[2];       // per-lane A-side k-slices, persistent per variant
    half8 sl_v[2][3];
    half8 pA[2], pG[2], pV[2];   // depth-2 B rotation (compile-time indexed)

#pragma unroll 1
    for (int t = 0; t < 4; ++t) {
        // all prior-variant feat readers are done past this barrier
        __syncthreads();

        const _Float16* Bl = Ball + t * 98304 + lane * 8;

        // ---- prologue: issue chunks 0,1 (complete during feat build) ----
        pA[0] = *(const half8*)(Bl + 0 * 1536);
        pG[0] = *(const half8*)(Bl + 0 * 1536 + 512);
        pV[0] = *(const half8*)(Bl + 0 * 1536 + 1024);
        pA[1] = *(const half8*)(Bl + 1 * 1536);
        pG[1] = *(const half8*)(Bl + 1 * 1536 + 512);
        pV[1] = *(const half8*)(Bl + 1 * 1536 + 1024);

        // ---- build variant-t features (float4 loads) ----
#pragma unroll
        for (int it = 0; it < 3; ++it) {
            int item = it * 192 + tid;        // 16 batches x 32 ch-groups
            if (item < 512) {
                int b  = item >> 5;
                int cg = item & 31;
                const float* bp = xg + b * 768 + cg * 4;
                float4_t v00 = *(const float4_t*)(bp);
                float4_t v01 = *(const float4_t*)(bp + 128);
                float4_t v02 = *(const float4_t*)(bp + 256);
                float4_t v10 = *(const float4_t*)(bp + 384);
                float4_t v11 = *(const float4_t*)(bp + 512);
                float4_t v12 = *(const float4_t*)(bp + 640);
                float4_t rs0 = v00 + v01 + v02, rs1 = v10 + v11 + v12;
                float4_t tot = rs0 + rs1;
                float4_t xv[6] = {v00, v01, v02, v10, v11, v12};
                float4_t rs[2] = {rs0, rs1};
                float4_t cs[3] = {v00 + v10, v01 + v11, v02 + v12};
#pragma unroll
                for (int p6 = 0; p6 < 6; ++p6) {
                    int i = p6 / 3, j = p6 % 3;
                    float4_t f;
                    if      (t == 0) f = xv[p6];
                    else if (t == 1) f = (rs[i] - xv[p6]) * 0.5f;
                    else if (t == 2) f = cs[j] - xv[p6];
                    else             f = (tot - rs[i] - cs[j] + xv[p6]) * 0.5f;
                    int pos = b * 6 + p6;
                    int base = pos * 128;
                    int pxs = pos & 7;
                    if (cg < 8) {   // s-rows: 4 contiguous halves, one b64 store
                        int row0 = cg * 4;
                        int addr = base + ((((row0 >> 3) ^ pxs) << 3) | (row0 & 7));
                        half4_t h4 = {(_Float16)f[0], (_Float16)f[1],
                                      (_Float16)f[2], (_Float16)f[3]};
                        *(half4_t*)(feat + addr) = h4;
                    } else {        // v-rows: scattered
#pragma unroll
                        for (int c4 = 0; c4 < 4; ++c4) {
                            int cc = cg * 4 + c4 - 32;
                            int row = 32 + (cc % 3) * 32 + cc / 3;
                            feat[base + ((((row >> 3) ^ pxs) << 3) | (row & 7))] =
                                (_Float16)f[c4];
                        }
                    }
                }
            }
        }
        __syncthreads();   // feat published (incl. lgkm drain)

        // ---- per-lane A-side slices, once per variant ----
#pragma unroll
        for (int kh = 0; kh < 2; ++kh) {
            sl_s[kh] = *(const half8*)(fpos + (((kh * 2 + q8) ^ px) << 3));
#pragma unroll
            for (int i = 0; i < 3; ++i)
                sl_v[kh][i] = *(const half8*)(fpos + (((4 + i * 4 + kh * 2 + q8) ^ px) << 3));
        }

        // ---- 64 chunks (u,kh); barrier-free, register depth-2 pipeline ----
#pragma unroll 1
        for (int cb = 0; cb < 4; ++cb) {
            // broadcast chunk for u = cb*8 .. cb*8+7 (ds_read, reg-resident)
            half8 bcS  = *(const half8*)(fpos + ((cb ^ px) << 3));
            half8 bcG0 = *(const half8*)(fpos + (((4 + cb) ^ px) << 3));
            half8 bcG1 = *(const half8*)(fpos + (((8 + cb) ^ px) << 3));
            half8 bcG2 = *(const half8*)(fpos + (((12 + cb) ^ px) << 3));
            const _Float16* BlC = Bl + (size_t)cb * 16 * 1536;

#pragma unroll
            for (int k = 0; k < 16; ++k) {
                const int sl = k & 1;        // chunk parity == k parity
                const int kh = k & 1;
                const int uu = k >> 1;       // 0..7, compile-time

                _Float16 su = bcS[uu];
                _Float16 g0 = bcG0[uu], g1 = bcG1[uu], g2 = bcG2[uu];

                __builtin_amdgcn_s_setprio(1);
                half8 af;
                // ---- ys: s.s^T ----
                af = sl_s[kh] * su;
                acc_s = __builtin_amdgcn_mfma_f32_32x32x16_f16(af, pA[sl], acc_s, 0, 0, 0);
                // ---- ys: Gram(v) ----
                af = sl_v[kh][0] * g0 + sl_v[kh][1] * g1 + sl_v[kh][2] * g2;
                acc_s = __builtin_amdgcn_mfma_f32_32x32x16_f16(af, pG[sl], acc_s, 0, 0, 0);
                // ---- yv: s[u] v[v,kc], V-frag shared across kc ----
#pragma unroll
                for (int kc = 0; kc < 3; ++kc) {
                    half8 afv = sl_v[kh][kc] * su;
                    acc_v[kc] = __builtin_amdgcn_mfma_f32_32x32x16_f16(afv, pV[sl], acc_v[kc], 0, 0, 0);
                }
                __builtin_amdgcn_s_setprio(0);

                // refill slot with chunk c+2 (consumed above; compiler
                // schedules the loads up into the MFMA cluster)
                if (k < 14 || cb < 3) {
                    pA[sl] = *(const half8*)(BlC + (k + 2) * 1536);
                    pG[sl] = *(const half8*)(BlC + (k + 2) * 1536 + 512);
                    pV[sl] = *(const half8*)(BlC + (k + 2) * 1536 + 1024);
                }
            }
        }
    }

    // ---- epilogue: 32x32 C/D layout col(n)=lane&31, row=(reg&3)+8*(reg>>2)+4*q8 ----
    // plain stores: let L2 merge the partial lines (NT caused 2.4x write amp).
    float* yg = y + (size_t)wg * (96 * 128);
    const int pb = wave * 32 + q8 * 4;
#pragma unroll
    for (int r = 0; r < 16; ++r) {
        int pos = pb + (r & 3) + 8 * (r >> 2);
        float* yp = yg + pos * 128;
        yp[mw] = acc_s[r];
        yp[32 + 3 * mw + 0] = acc_v[0][r];
        yp[32 + 3 * mw + 1] = acc_v[1][r];
        yp[32 + 3 * mw + 2] = acc_v[2][r];
    }
}

extern "C" void kernel_launch(void* const* d_in, const int* in_sizes, int n_in,
                              void* d_out, int out_size, void* d_ws, size_t ws_size,
                              hipStream_t stream) {
    const float* x  = (const float*)d_in[0];
    const float* Wa = (const float*)d_in[1];
    const float* Wb = (const float*)d_in[2];
    const float* Wc = (const float*)d_in[3];
    const float* Wd = (const float*)d_in[4];
    float* y = (float*)d_out;

    _Float16* Ball = (_Float16*)d_ws;          // 393216 half = 768 KB

    int nbatch = in_sizes[0] / 768;            // 16384
    int nwg = nbatch / 16;                     // 1024 = 4 blocks/CU exactly

    prep_kernel<<<192, 256, 0, stream>>>(Wa, Wb, Wc, Wd, Ball);
    petp_main<<<nwg, 192, 0, stream>>>(x, Ball, y);
}